// Round 1
// baseline (337.647 us; speedup 1.0000x reference)
//
#include <hip/hip_runtime.h>
#include <hip/hip_bf16.h>
#include <math.h>

// Problem constants
#define B_ 4
#define T_ 4096
#define C_ 1024
#define H_ 128
#define SCALE 0.08838834764831845f  // 1/sqrt(128)

typedef __attribute__((ext_vector_type(8))) short bf16x8;
typedef __attribute__((ext_vector_type(4))) float f32x4;

__device__ __forceinline__ unsigned short f2bf(float f) {
    union { float f; unsigned u; } x; x.f = f;
    unsigned r = x.u + 0x7FFF + ((x.u >> 16) & 1);
    return (unsigned short)(r >> 16);
}

// ---------------------------------------------------------------------------
// Kernel 1: W [C,H] fp32  ->  Wt [t][h][c] bf16  (transposed, cast)
// ---------------------------------------------------------------------------
__global__ __launch_bounds__(256) void wtrans_kernel(
        const float* __restrict__ Wk, const float* __restrict__ Wq,
        const float* __restrict__ Wv, unsigned short* __restrict__ Wt) {
    int tid = blockIdx.x * 256 + threadIdx.x;   // 0 .. 393215
    int t = tid >> 17;                          // / 131072
    int r = tid & 131071;                       // index into W[t] (c*128 + h)
    int c = r >> 7;
    int h = r & 127;
    const float* W = (t == 0) ? Wk : (t == 1) ? Wq : Wv;
    Wt[t * 131072 + h * 1024 + c] = f2bf(W[r]); // coalesced read, scattered write (tiny)
}

// ---------------------------------------------------------------------------
// Kernel 2: QKV projection GEMM.  M=16384, N=384 (k|q|v), K=1024, bf16 MFMA.
// One block = 64 M-rows x all 384 N-cols. 4 waves, each 16 rows x 384 cols.
// ---------------------------------------------------------------------------
#define BM 64
#define BK 64
__global__ __launch_bounds__(256) void qkv_gemm(
        const float* __restrict__ x, const unsigned short* __restrict__ Wt,
        unsigned short* __restrict__ qkv) {
    __shared__ unsigned short As[BM][72];    // 64x64 bf16, pad 8 -> 2-way conflicts
    __shared__ unsigned short Bs[384][72];   // 384x64 bf16 (col-major of W chunk)

    const int m0 = blockIdx.x * BM;
    const int tid = threadIdx.x;
    const int lane = tid & 63;
    const int w = tid >> 6;
    const int fr = lane & 15;      // frag row/col
    const int fq = lane >> 4;      // k-group

    f32x4 acc[24];
#pragma unroll
    for (int i = 0; i < 24; i++) acc[i] = f32x4{0.f, 0.f, 0.f, 0.f};

    for (int k0 = 0; k0 < C_; k0 += BK) {
        __syncthreads();
        // stage A: 64 rows x 64 k, fp32 -> bf16. 16 floats per thread.
        {
            int row = tid >> 2;
            int coff = (tid & 3) * 16;
            const float* src = x + (long)(m0 + row) * C_ + k0 + coff;
            unsigned short tmp[16];
#pragma unroll
            for (int i = 0; i < 4; i++) {
                float4 v = ((const float4*)src)[i];
                tmp[i*4+0] = f2bf(v.x); tmp[i*4+1] = f2bf(v.y);
                tmp[i*4+2] = f2bf(v.z); tmp[i*4+3] = f2bf(v.w);
            }
            uint4* dst = (uint4*)&As[row][coff];
            dst[0] = ((uint4*)tmp)[0];
            dst[1] = ((uint4*)tmp)[1];
        }
        // stage B: 384 rows (t*128+h) x 64 k from Wt (already transposed bf16)
        {
#pragma unroll
            for (int i = 0; i < 12; i++) {
                int idx = tid + i * 256;         // 0..3071 chunks of 8
                int row = idx >> 3;              // 0..383
                int coff = (idx & 7) * 8;
                *(uint4*)&Bs[row][coff] =
                    *(const uint4*)(Wt + (long)row * 1024 + k0 + coff);
            }
        }
        __syncthreads();

        bf16x8 a0 = *(const bf16x8*)&As[w*16 + fr][fq*8];
        bf16x8 a1 = *(const bf16x8*)&As[w*16 + fr][32 + fq*8];
#pragma unroll
        for (int nf = 0; nf < 24; nf++) {
            bf16x8 b0 = *(const bf16x8*)&Bs[nf*16 + fr][fq*8];
            bf16x8 b1 = *(const bf16x8*)&Bs[nf*16 + fr][32 + fq*8];
            acc[nf] = __builtin_amdgcn_mfma_f32_16x16x32_bf16(a0, b0, acc[nf], 0, 0, 0);
            acc[nf] = __builtin_amdgcn_mfma_f32_16x16x32_bf16(a1, b1, acc[nf], 0, 0, 0);
        }
    }
    // epilogue: D layout col=lane&15, row=(lane>>4)*4+r. Write bf16 q/k/v.
#pragma unroll
    for (int nf = 0; nf < 24; nf++) {
        int t = nf >> 3;
        int col = (nf & 7) * 16 + fr;
#pragma unroll
        for (int r = 0; r < 4; r++) {
            int row = m0 + w*16 + fq*4 + r;
            qkv[(long)t * (16384L * 128) + (long)row * 128 + col] = f2bf(acc[nf][r]);
        }
    }
}

// ---------------------------------------------------------------------------
// Kernel 3: causal flash attention. qkv bf16 [3][B*T][128] (k,q,v), out fp32.
// Block = (q-tile of 64, batch). 4 waves x 16 q-rows. KV tiles of 32.
// ---------------------------------------------------------------------------
#define QB 64
#define KB 32
__global__ __launch_bounds__(256) void flash_kernel(
        const unsigned short* __restrict__ qkv, float* __restrict__ out) {
    __shared__ unsigned short k_lds[KB][136];   // pad: stride 272B -> 2-way
    __shared__ unsigned short v_lds[H_][40];    // transposed V, stride 80B -> 2-way
    __shared__ unsigned short p_lds[4][16][40]; // per-wave P roundtrip

    const int b = blockIdx.y;
    const int q0 = blockIdx.x * QB;
    const int tid = threadIdx.x;
    const int w = tid >> 6;
    const int lane = tid & 63;
    const int fr = lane & 15;
    const int fq = lane >> 4;

    const unsigned short* kb = qkv;
    const unsigned short* qb = qkv + 2097152;
    const unsigned short* vb = qkv + 4194304;
    const unsigned short* kbase = kb + (long)b * T_ * H_;
    const unsigned short* vbase = vb + (long)b * T_ * H_;

    // Q fragments (A layout: row = fr, k = ks*32 + fq*8 + j)
    bf16x8 qf[4];
    {
        const unsigned short* qptr = qb + ((long)b * T_ + q0 + w*16 + fr) * H_;
#pragma unroll
        for (int ks = 0; ks < 4; ks++)
            qf[ks] = *(const bf16x8*)(qptr + ks*32 + fq*8);
    }

    f32x4 acc[8];
#pragma unroll
    for (int i = 0; i < 8; i++) acc[i] = f32x4{0.f, 0.f, 0.f, 0.f};
    float m_r[4], l_r[4];
#pragma unroll
    for (int r = 0; r < 4; r++) { m_r[r] = -INFINITY; l_r[r] = 0.f; }

    const int ntiles = (q0 + QB) / KB;
    for (int t = 0; t < ntiles; t++) {
        const int kv0 = t * KB;
        __syncthreads();   // previous tile's LDS reads done
        // stage K tile: 32 x 128 bf16
#pragma unroll
        for (int i = 0; i < 2; i++) {
            int idx = tid + i * 256;
            int row = idx >> 4;
            int coff = (idx & 15) * 8;
            *(uint4*)&k_lds[row][coff] =
                *(const uint4*)(kbase + (long)(kv0 + row) * H_ + coff);
        }
        // stage V tile transposed: v_lds[h][kv]
#pragma unroll
        for (int i = 0; i < 2; i++) {
            int idx = tid + i * 256;
            int row = idx >> 4;
            int coff = (idx & 15) * 8;
            uint4 d = *(const uint4*)(vbase + (long)(kv0 + row) * H_ + coff);
            unsigned short tmp[8]; *(uint4*)tmp = d;
#pragma unroll
            for (int j = 0; j < 8; j++) v_lds[coff + j][row] = tmp[j];
        }
        __syncthreads();

        // S = Q K^T : two 16x16 frags over kv
        f32x4 s[2];
        s[0] = f32x4{0.f,0.f,0.f,0.f}; s[1] = f32x4{0.f,0.f,0.f,0.f};
#pragma unroll
        for (int sf = 0; sf < 2; sf++) {
#pragma unroll
            for (int ks = 0; ks < 4; ks++) {
                bf16x8 kf = *(const bf16x8*)&k_lds[sf*16 + fr][ks*32 + fq*8];
                s[sf] = __builtin_amdgcn_mfma_f32_16x16x32_bf16(qf[ks], kf, s[sf], 0, 0, 0);
            }
        }

        // scale + causal mask; rows = q0+w*16+fq*4+r, cols = kv0+sf*16+fr
        float rowmax[4], p0v[4], p1v[4];
#pragma unroll
        for (int r = 0; r < 4; r++) {
            int qr = q0 + w*16 + fq*4 + r;
            float s0 = s[0][r] * SCALE;
            float s1 = s[1][r] * SCALE;
            if (kv0 + fr > qr)      s0 = -INFINITY;
            if (kv0 + 16 + fr > qr) s1 = -INFINITY;
            s[0][r] = s0; s[1][r] = s1;
            rowmax[r] = fmaxf(s0, s1);
        }
#pragma unroll
        for (int msk = 1; msk < 16; msk <<= 1) {
#pragma unroll
            for (int r = 0; r < 4; r++)
                rowmax[r] = fmaxf(rowmax[r], __shfl_xor(rowmax[r], msk, 64));
        }
        float rowsum[4], alpha[4];
#pragma unroll
        for (int r = 0; r < 4; r++) {
            float mn = fmaxf(m_r[r], rowmax[r]);
            bool valid = mn > -INFINITY;
            float a  = valid ? __expf(m_r[r] - mn) : 1.0f;
            float p0 = valid ? __expf(s[0][r] - mn) : 0.0f;
            float p1 = valid ? __expf(s[1][r] - mn) : 0.0f;
            m_r[r] = mn; alpha[r] = a;
            p0v[r] = p0; p1v[r] = p1;
            rowsum[r] = p0 + p1;
        }
#pragma unroll
        for (int msk = 1; msk < 16; msk <<= 1) {
#pragma unroll
            for (int r = 0; r < 4; r++)
                rowsum[r] += __shfl_xor(rowsum[r], msk, 64);
        }
#pragma unroll
        for (int r = 0; r < 4; r++) l_r[r] = l_r[r] * alpha[r] + rowsum[r];
#pragma unroll
        for (int hf = 0; hf < 8; hf++)
#pragma unroll
            for (int r = 0; r < 4; r++) acc[hf][r] *= alpha[r];

        // write P (D layout) to per-wave LDS, reread in A layout
#pragma unroll
        for (int r = 0; r < 4; r++) {
            p_lds[w][fq*4 + r][fr]      = f2bf(p0v[r]);
            p_lds[w][fq*4 + r][16 + fr] = f2bf(p1v[r]);
        }
        __syncthreads();   // orders p_lds writes (uniform across block)

        bf16x8 pf = *(const bf16x8*)&p_lds[w][fr][fq*8];
#pragma unroll
        for (int hf = 0; hf < 8; hf++) {
            bf16x8 vf = *(const bf16x8*)&v_lds[hf*16 + fr][fq*8];
            acc[hf] = __builtin_amdgcn_mfma_f32_16x16x32_bf16(pf, vf, acc[hf], 0, 0, 0);
        }
    }

    // epilogue: out = acc / l
#pragma unroll
    for (int hf = 0; hf < 8; hf++) {
#pragma unroll
        for (int r = 0; r < 4; r++) {
            int qr = q0 + w*16 + fq*4 + r;
            out[((long)b * T_ + qr) * H_ + hf*16 + fr] = acc[hf][r] / l_r[r];
        }
    }
}

// ---------------------------------------------------------------------------
extern "C" void kernel_launch(void* const* d_in, const int* in_sizes, int n_in,
                              void* d_out, int out_size, void* d_ws, size_t ws_size,
                              hipStream_t stream) {
    (void)in_sizes; (void)n_in; (void)out_size; (void)ws_size;
    const float* x  = (const float*)d_in[0];
    const float* Wk = (const float*)d_in[1];
    const float* Wq = (const float*)d_in[2];
    const float* Wv = (const float*)d_in[3];
    float* out = (float*)d_out;

    unsigned short* Wt  = (unsigned short*)d_ws;     // 393216 bf16
    unsigned short* qkv = Wt + 393216;               // 3 x 2097152 bf16 (k,q,v)

    wtrans_kernel<<<1536, 256, 0, stream>>>(Wk, Wq, Wv, Wt);
    qkv_gemm<<<256, 256, 0, stream>>>(x, Wt, qkv);
    flash_kernel<<<dim3(64, 4), 256, 0, stream>>>(qkv, out);
}

// Round 2
// 193.488 us; speedup vs baseline: 1.7451x; 1.7451x over previous
//
#include <hip/hip_runtime.h>
#include <hip/hip_bf16.h>
#include <math.h>

// Problem constants
#define B_ 4
#define T_ 4096
#define C_ 1024
#define H_ 128
#define SCALE 0.08838834764831845f  // 1/sqrt(128)

typedef __attribute__((ext_vector_type(8))) short bf16x8;
typedef __attribute__((ext_vector_type(4))) float f32x4;

__device__ __forceinline__ unsigned short f2bf(float f) {
    union { float f; unsigned u; } x; x.f = f;
    unsigned r = x.u + 0x7FFF + ((x.u >> 16) & 1);
    return (unsigned short)(r >> 16);
}
__device__ __forceinline__ float bf2f(unsigned short u) {
    union { unsigned u; float f; } x; x.u = ((unsigned)u) << 16;
    return x.f;
}

// ---------------------------------------------------------------------------
// Kernel 1: W [C,H] fp32  ->  Wt [t][h][c] bf16  (transposed, cast)
// ---------------------------------------------------------------------------
__global__ __launch_bounds__(256) void wtrans_kernel(
        const float* __restrict__ Wk, const float* __restrict__ Wq,
        const float* __restrict__ Wv, unsigned short* __restrict__ Wt) {
    int tid = blockIdx.x * 256 + threadIdx.x;   // 0 .. 393215
    int t = tid >> 17;
    int r = tid & 131071;
    int c = r >> 7;
    int h = r & 127;
    const float* W = (t == 0) ? Wk : (t == 1) ? Wq : Wv;
    Wt[t * 131072 + h * 1024 + c] = f2bf(W[r]);
}

// ---------------------------------------------------------------------------
// Kernel 2: QKV projection GEMM.  M=16384, N=384 (k|q|v), K=1024, bf16 MFMA.
// ---------------------------------------------------------------------------
#define BM 64
#define BK 64
__global__ __launch_bounds__(256) void qkv_gemm(
        const float* __restrict__ x, const unsigned short* __restrict__ Wt,
        unsigned short* __restrict__ qkv) {
    __shared__ unsigned short As[BM][72];
    __shared__ unsigned short Bs[384][72];

    const int m0 = blockIdx.x * BM;
    const int tid = threadIdx.x;
    const int lane = tid & 63;
    const int w = tid >> 6;
    const int fr = lane & 15;
    const int fq = lane >> 4;

    f32x4 acc[24];
#pragma unroll
    for (int i = 0; i < 24; i++) acc[i] = f32x4{0.f, 0.f, 0.f, 0.f};

    for (int k0 = 0; k0 < C_; k0 += BK) {
        __syncthreads();
        {
            int row = tid >> 2;
            int coff = (tid & 3) * 16;
            const float* src = x + (long)(m0 + row) * C_ + k0 + coff;
            unsigned short tmp[16];
#pragma unroll
            for (int i = 0; i < 4; i++) {
                float4 v = ((const float4*)src)[i];
                tmp[i*4+0] = f2bf(v.x); tmp[i*4+1] = f2bf(v.y);
                tmp[i*4+2] = f2bf(v.z); tmp[i*4+3] = f2bf(v.w);
            }
            uint4* dst = (uint4*)&As[row][coff];
            dst[0] = ((uint4*)tmp)[0];
            dst[1] = ((uint4*)tmp)[1];
        }
        {
#pragma unroll
            for (int i = 0; i < 12; i++) {
                int idx = tid + i * 256;
                int row = idx >> 3;
                int coff = (idx & 7) * 8;
                *(uint4*)&Bs[row][coff] =
                    *(const uint4*)(Wt + (long)row * 1024 + k0 + coff);
            }
        }
        __syncthreads();

        bf16x8 a0 = *(const bf16x8*)&As[w*16 + fr][fq*8];
        bf16x8 a1 = *(const bf16x8*)&As[w*16 + fr][32 + fq*8];
#pragma unroll
        for (int nf = 0; nf < 24; nf++) {
            bf16x8 b0 = *(const bf16x8*)&Bs[nf*16 + fr][fq*8];
            bf16x8 b1 = *(const bf16x8*)&Bs[nf*16 + fr][32 + fq*8];
            acc[nf] = __builtin_amdgcn_mfma_f32_16x16x32_bf16(a0, b0, acc[nf], 0, 0, 0);
            acc[nf] = __builtin_amdgcn_mfma_f32_16x16x32_bf16(a1, b1, acc[nf], 0, 0, 0);
        }
    }
#pragma unroll
    for (int nf = 0; nf < 24; nf++) {
        int t = nf >> 3;
        int col = (nf & 7) * 16 + fr;
#pragma unroll
        for (int r = 0; r < 4; r++) {
            int row = m0 + w*16 + fq*4 + r;
            qkv[(long)t * (16384L * 128) + (long)row * 128 + col] = f2bf(acc[nf][r]);
        }
    }
}

// ---------------------------------------------------------------------------
// Kernel 2b: V [B*T][128] -> vT [B][128][T]  (bf16 transpose via LDS)
// ---------------------------------------------------------------------------
__global__ __launch_bounds__(256) void vtrans_kernel(
        const unsigned short* __restrict__ v, unsigned short* __restrict__ vT) {
    __shared__ unsigned short tile[64][136];
    const int t0 = (blockIdx.x & 63) * 64;
    const int b = blockIdx.x >> 6;
    const int tid = threadIdx.x;
#pragma unroll
    for (int i = 0; i < 4; i++) {
        int idx = tid + i * 256;
        int tr = idx >> 4, coff = (idx & 15) * 8;
        *(uint4*)&tile[tr][coff] =
            *(const uint4*)(v + ((long)(b * T_ + t0 + tr)) * H_ + coff);
    }
    __syncthreads();
#pragma unroll
    for (int i = 0; i < 4; i++) {
        int idx = tid + i * 256;
        int h = idx >> 3, ts = (idx & 7) * 8;
        unsigned short tmp[8];
#pragma unroll
        for (int j = 0; j < 8; j++) tmp[j] = tile[ts + j][h];
        *(uint4*)(vT + ((long)(b * H_ + h)) * T_ + t0 + ts) = *(uint4*)tmp;
    }
}

// ---------------------------------------------------------------------------
// Kernel 3: causal flash attention, KV-split-2 with balanced pairing.
// Block n: j=n&63, b=(n>>6)&3, half=n>>8; q-tile = half? 63-j : j.
// 4 waves x 16 q-rows, KV tiles of 64. Writes normalized bf16 partials + m,l.
// ---------------------------------------------------------------------------
#define QB 64
#define KB 64
__global__ __launch_bounds__(256) void flash2_kernel(
        const unsigned short* __restrict__ qkv,
        const unsigned short* __restrict__ vT,
        unsigned short* __restrict__ po,
        float* __restrict__ pm, float* __restrict__ pl) {
    __shared__ unsigned short k_lds[KB][136];
    __shared__ unsigned short v_lds[H_][72];
    __shared__ unsigned short p_lds[4][16][72];

    const int n = blockIdx.x;
    const int j = n & 63;
    const int b = (n >> 6) & 3;
    const int half = n >> 8;
    const int qt = half ? (63 - j) : j;
    const int q0 = qt * QB;
    const int nt = qt + 1;                 // total KB-tiles for this q-tile
    const int nh0 = (nt + 1) >> 1;
    const int t0 = half ? nh0 : 0;
    const int t1 = half ? nt : nh0;

    const int tid = threadIdx.x;
    const int w = tid >> 6;
    const int lane = tid & 63;
    const int fr = lane & 15;
    const int fq = lane >> 4;

    const unsigned short* kbase = qkv + (long)b * T_ * H_;

    bf16x8 qf[4];
    {
        const unsigned short* qptr = qkv + 2097152 + ((long)b * T_ + q0 + w*16 + fr) * H_;
#pragma unroll
        for (int ks = 0; ks < 4; ks++)
            qf[ks] = *(const bf16x8*)(qptr + ks*32 + fq*8);
    }

    f32x4 acc[8];
#pragma unroll
    for (int i = 0; i < 8; i++) acc[i] = f32x4{0.f, 0.f, 0.f, 0.f};
    float m_r[4], l_r[4];
#pragma unroll
    for (int r = 0; r < 4; r++) { m_r[r] = -INFINITY; l_r[r] = 0.f; }

    for (int t = t0; t < t1; t++) {
        const int kv0 = t * KB;
        __syncthreads();
        // stage K tile: 64 x 128 bf16, b128 writes
#pragma unroll
        for (int i = 0; i < 4; i++) {
            int idx = tid + i * 256;
            int row = idx >> 4;
            int coff = (idx & 15) * 8;
            *(uint4*)&k_lds[row][coff] =
                *(const uint4*)(kbase + (long)(kv0 + row) * H_ + coff);
        }
        // stage V tile from pre-transposed vT: v_lds[h][kv], b128 writes
#pragma unroll
        for (int i = 0; i < 4; i++) {
            int idx = tid + i * 256;
            int h = idx >> 3;
            int coff = (idx & 7) * 8;
            *(uint4*)&v_lds[h][coff] =
                *(const uint4*)(vT + ((long)(b * H_ + h)) * T_ + kv0 + coff);
        }
        __syncthreads();

        // S = Q K^T : 4 16x16 frags over 64 kv cols
        f32x4 s[4];
#pragma unroll
        for (int sf = 0; sf < 4; sf++) s[sf] = f32x4{0.f,0.f,0.f,0.f};
#pragma unroll
        for (int sf = 0; sf < 4; sf++) {
#pragma unroll
            for (int ks = 0; ks < 4; ks++) {
                bf16x8 kf = *(const bf16x8*)&k_lds[sf*16 + fr][ks*32 + fq*8];
                s[sf] = __builtin_amdgcn_mfma_f32_16x16x32_bf16(qf[ks], kf, s[sf], 0, 0, 0);
            }
        }

        const bool diag = (kv0 == q0);
        float rowmax[4];
#pragma unroll
        for (int r = 0; r < 4; r++) {
            int qr = q0 + w*16 + fq*4 + r;
            float mx = -INFINITY;
#pragma unroll
            for (int sf = 0; sf < 4; sf++) {
                float sv = s[sf][r] * SCALE;
                if (diag && (kv0 + sf*16 + fr > qr)) sv = -INFINITY;
                s[sf][r] = sv;
                mx = fmaxf(mx, sv);
            }
            rowmax[r] = mx;
        }
#pragma unroll
        for (int msk = 1; msk < 16; msk <<= 1) {
#pragma unroll
            for (int r = 0; r < 4; r++)
                rowmax[r] = fmaxf(rowmax[r], __shfl_xor(rowmax[r], msk, 64));
        }
        float alpha[4], rowsum[4];
        float pv[4][4];
#pragma unroll
        for (int r = 0; r < 4; r++) {
            float mn = fmaxf(m_r[r], rowmax[r]);
            float a = __expf(m_r[r] - mn);
            m_r[r] = mn; alpha[r] = a;
            float sum = 0.f;
#pragma unroll
            for (int sf = 0; sf < 4; sf++) {
                float p = __expf(s[sf][r] - mn);
                pv[sf][r] = p;
                sum += p;
            }
            rowsum[r] = sum;
        }
#pragma unroll
        for (int msk = 1; msk < 16; msk <<= 1) {
#pragma unroll
            for (int r = 0; r < 4; r++)
                rowsum[r] += __shfl_xor(rowsum[r], msk, 64);
        }
#pragma unroll
        for (int r = 0; r < 4; r++) l_r[r] = l_r[r] * alpha[r] + rowsum[r];
#pragma unroll
        for (int hf = 0; hf < 8; hf++)
#pragma unroll
            for (int r = 0; r < 4; r++) acc[hf][r] *= alpha[r];

        // write P (D layout) to per-wave LDS, reread in A layout (wave-local)
#pragma unroll
        for (int r = 0; r < 4; r++)
#pragma unroll
            for (int sf = 0; sf < 4; sf++)
                p_lds[w][fq*4 + r][sf*16 + fr] = f2bf(pv[sf][r]);
        __asm__ volatile("s_waitcnt lgkmcnt(0)" ::: "memory");

        bf16x8 pf0 = *(const bf16x8*)&p_lds[w][fr][fq*8];
        bf16x8 pf1 = *(const bf16x8*)&p_lds[w][fr][32 + fq*8];
#pragma unroll
        for (int hf = 0; hf < 8; hf++) {
            bf16x8 vf0 = *(const bf16x8*)&v_lds[hf*16 + fr][fq*8];
            bf16x8 vf1 = *(const bf16x8*)&v_lds[hf*16 + fr][32 + fq*8];
            acc[hf] = __builtin_amdgcn_mfma_f32_16x16x32_bf16(pf0, vf0, acc[hf], 0, 0, 0);
            acc[hf] = __builtin_amdgcn_mfma_f32_16x16x32_bf16(pf1, vf1, acc[hf], 0, 0, 0);
        }
    }

    // write normalized bf16 partials + m,l
    const long pbase = ((long)half * 4 + b) * T_;
#pragma unroll
    for (int r = 0; r < 4; r++) {
        int qr = q0 + w*16 + fq*4 + r;
        float linv = (l_r[r] > 0.f) ? (1.0f / l_r[r]) : 0.f;
#pragma unroll
        for (int hf = 0; hf < 8; hf++)
            po[(pbase + qr) * H_ + hf*16 + fr] = f2bf(acc[hf][r] * linv);
        if (fr == 0) {
            pm[pbase + qr] = m_r[r];
            pl[pbase + qr] = l_r[r];
        }
    }
}

// ---------------------------------------------------------------------------
// Kernel 4: combine the two KV-halves
// ---------------------------------------------------------------------------
__global__ __launch_bounds__(256) void combine_kernel(
        const unsigned short* __restrict__ po, const float* __restrict__ pm,
        const float* __restrict__ pl, float* __restrict__ out) {
    int idx = blockIdx.x * 256 + threadIdx.x;   // 0..262143
    int row = idx >> 4;                         // b*T + q
    int seg = idx & 15;
    float m0 = pm[row],        l0 = pl[row];
    float m1 = pm[16384 + row], l1 = pl[16384 + row];
    float m = fmaxf(m0, m1);
    float w0 = (l0 > 0.f) ? __expf(m0 - m) * l0 : 0.f;
    float w1 = (l1 > 0.f) ? __expf(m1 - m) * l1 : 0.f;
    float inv = 1.0f / (w0 + w1);
    w0 *= inv; w1 *= inv;
    const unsigned short* p0 = po + (long)row * H_ + seg * 8;
    const unsigned short* p1 = p0 + 2097152;
    unsigned short ua[8], ub[8];
    *(uint4*)ua = *(const uint4*)p0;
    *(uint4*)ub = *(const uint4*)p1;
    float* o = out + (long)row * H_ + seg * 8;
#pragma unroll
    for (int j2 = 0; j2 < 8; j2++)
        o[j2] = w0 * bf2f(ua[j2]) + w1 * bf2f(ub[j2]);
}

// ---------------------------------------------------------------------------
extern "C" void kernel_launch(void* const* d_in, const int* in_sizes, int n_in,
                              void* d_out, int out_size, void* d_ws, size_t ws_size,
                              hipStream_t stream) {
    (void)in_sizes; (void)n_in; (void)out_size; (void)ws_size;
    const float* x  = (const float*)d_in[0];
    const float* Wk = (const float*)d_in[1];
    const float* Wq = (const float*)d_in[2];
    const float* Wv = (const float*)d_in[3];
    float* out = (float*)d_out;

    unsigned short* Wt  = (unsigned short*)d_ws;       // 393216
    unsigned short* qkv = Wt + 393216;                 // 3 x 2097152 (k,q,v)
    unsigned short* vT  = qkv + 6291456;               // 2097152
    unsigned short* po  = vT + 2097152;                // 2 x 2097152
    float* pm = (float*)(po + 4194304);                // 2 x 16384
    float* pl = pm + 32768;                            // 2 x 16384

    wtrans_kernel<<<1536, 256, 0, stream>>>(Wk, Wq, Wv, Wt);
    qkv_gemm<<<256, 256, 0, stream>>>(x, Wt, qkv);
    vtrans_kernel<<<256, 256, 0, stream>>>(qkv + 4194304, vT);
    flash2_kernel<<<512, 256, 0, stream>>>(qkv, vT, po, pm, pl);
    combine_kernel<<<1024, 256, 0, stream>>>(po, pm, pl, out);
}